// Round 10
// baseline (3630.977 us; speedup 1.0000x reference)
//
#include <hip/hip_runtime.h>
#include <math.h>

#define N_NODES 100000
#define N_EDGES 3200000
#define NPB 128                              // nodes per bucket
#define NBUCK ((N_NODES + NPB - 1) / NPB)    // 782

typedef unsigned short ushort_t;

static __device__ __forceinline__ float bf2f(ushort_t u) {
    return __uint_as_float(((unsigned int)u) << 16);
}
static __device__ __forceinline__ unsigned int f2bf_u(float f) {
    unsigned int x = __float_as_uint(f);
    unsigned int lsb = (x >> 16) & 1u;
    x += 0x7fffu + lsb;  // round-to-nearest-even
    return x >> 16;
}
static __device__ __forceinline__ ushort_t f2bf(float f) { return (ushort_t)f2bf_u(f); }

// ---- pass A: bucket histogram (LDS-aggregated) ----
__global__ void bucket_hist_kernel(const int* __restrict__ col, int* __restrict__ bucketCnt) {
    __shared__ int h[NBUCK];
    for (int t = threadIdx.x; t < NBUCK; t += 256) h[t] = 0;
    __syncthreads();
    for (int e = blockIdx.x * 256 + threadIdx.x; e < N_EDGES; e += gridDim.x * 256)
        atomicAdd(&h[col[e] >> 7], 1);
    __syncthreads();
    for (int t = threadIdx.x; t < NBUCK; t += 256)
        if (h[t]) atomicAdd(&bucketCnt[t], h[t]);
}

// ---- pass B: scan bucket counts -> bucketOff; init bcursor ----
__global__ void bucket_scan_kernel(const int* __restrict__ bucketCnt, int* __restrict__ bucketOff,
                                   int* __restrict__ bcursor) {
    __shared__ int tmp[1024];
    int tx = threadIdx.x;
    int v = (tx < NBUCK) ? bucketCnt[tx] : 0;
    tmp[tx] = v;
    __syncthreads();
    for (int off = 1; off < 1024; off <<= 1) {
        int t = (tx >= off) ? tmp[tx - off] : 0;
        __syncthreads();
        if (tx >= off) tmp[tx] += t;
        __syncthreads();
    }
    if (tx < NBUCK) {
        int o = tmp[tx] - v;
        bucketOff[tx] = o;
        bcursor[tx] = o;
    }
}

// ---- pass C: bin edges by bucket (block-aggregated append); writes {row, col} ----
__global__ void bin_kernel(const int* __restrict__ row, const int* __restrict__ col,
                           int* __restrict__ bcursor, int2* __restrict__ tmpE) {
    __shared__ int hist[NBUCK];
    __shared__ int chunkOff[NBUCK];
    int tx = threadIdx.x;
    for (int t = tx; t < NBUCK; t += 512) hist[t] = 0;
    __syncthreads();
    int base = blockIdx.x * 4096;
    int myc[8], myr[8], myrank[8];
#pragma unroll 8
    for (int k = 0; k < 8; ++k) {
        int idx = base + k * 512 + tx;
        bool valid = idx < N_EDGES;
        int c = valid ? col[idx] : 0;
        int r = valid ? row[idx] : 0;
        myc[k] = c;
        myr[k] = r;
        myrank[k] = valid ? atomicAdd(&hist[c >> 7], 1) : 0;
    }
    __syncthreads();
    for (int t = tx; t < NBUCK; t += 512) {
        int hv = hist[t];
        chunkOff[t] = hv ? atomicAdd(&bcursor[t], hv) : 0;
    }
    __syncthreads();
#pragma unroll 8
    for (int k = 0; k < 8; ++k) {
        int idx = base + k * 512 + tx;
        if (idx < N_EDGES) {
            int pos = chunkOff[myc[k] >> 7] + myrank[k];
            tmpE[pos] = make_int2(myr[k], myc[k]);
        }
    }
}

// ---- pass D: per-bucket degree -> isq; labels reduction -> npos ----
__global__ void csrlite_kernel(const int2* __restrict__ eB, const int* __restrict__ bOff,
                               const int* __restrict__ bCnt, float* __restrict__ isq,
                               const float* __restrict__ labels, float* __restrict__ npos) {
    __shared__ int scnt[NPB];
    __shared__ float red[NPB];
    int b = blockIdx.x, lo = b << 7, tx = threadIdx.x;
    scnt[tx] = 0;
    __syncthreads();
    int base = bOff[b], cnt = bCnt[b];
    for (int t = tx; t < cnt; t += NPB) atomicAdd(&scnt[eB[base + t].y & 127], 1);
    __syncthreads();
    int node = lo + tx;
    float lab = 0.0f;
    if (node < N_NODES) {
        isq[node] = rsqrtf((float)scnt[tx] + 1.0f);
        lab = labels[node];
    }
    red[tx] = lab;
    __syncthreads();
    for (int s = NPB / 2; s > 0; s >>= 1) {
        if (tx < s) red[tx] += red[tx + s];
        __syncthreads();
    }
    if (tx == 0) atomicAdd(npos, red[0]);
}

// ---- pass E: in-place {row,col} -> {(colLocal<<17)|row, norm} ----
__global__ void normpack_kernel(int2* __restrict__ eB, const float* __restrict__ isq) {
    int e = blockIdx.x * 256 + threadIdx.x;
    if (e < N_EDGES) {
        int2 rc = eB[e];
        float nv = isq[rc.x] * isq[rc.y];
        eB[e] = make_int2(((rc.y & 127) << 17) | rc.x, __float_as_int(nv));
    }
}

// ---- x (fp32 N*32) -> bf16 table ----
__global__ void xcast_kernel(const float* __restrict__ x, ushort_t* __restrict__ xbf) {
    int i = blockIdx.x * 256 + threadIdx.x;  // group of 4
    if (i < (N_NODES * 32) / 4) {
        float4 v = ((const float4*)x)[i];
        ushort4 o;
        o.x = f2bf(v.x); o.y = f2bf(v.y); o.z = f2bf(v.z); o.w = f2bf(v.w);
        ((ushort4*)xbf)[i] = o;
    }
}

// ---- pack W1/W2/W3 into per-lane bf16x2 column tables ----
// layout: slot k2 in [0,80): [0,16)=W1, [16,48)=W2, [48,80)=W3; wp[k2*64+lane]
__global__ void wpack_kernel(const float* __restrict__ W1, const float* __restrict__ W2,
                             const float* __restrict__ W3, unsigned int* __restrict__ wp) {
    int t = blockIdx.x * 256 + threadIdx.x;
    if (t >= 80 * 64) return;
    int k2 = t >> 6, l = t & 63;
    const float* W;
    int kk;
    if (k2 < 16) { W = W1; kk = k2; }
    else if (k2 < 48) { W = W2; kk = k2 - 16; }
    else { W = W3; kk = k2 - 48; }
    float lo = W[(2 * kk) * 64 + l];
    float hi = W[(2 * kk + 1) * 64 + l];
    wp[t] = (f2bf_u(hi) << 16) | f2bf_u(lo);
}

// ---- layers 2/3: bucket-LDS aggregation + fused GEMM epilogue ----
// block = 512 thr (8 waves) owns one 128-node bucket; agg[128][64] fp32 in LDS
__global__ void __launch_bounds__(512) fusedAgg64_kernel(
    const int2* __restrict__ eB, const int* __restrict__ bOff, const int* __restrict__ bCnt,
    const ushort_t* __restrict__ hin, const float* __restrict__ isq,
    const unsigned int* __restrict__ wpG, const float* __restrict__ bias,
    ushort_t* __restrict__ hout) {
    __shared__ float agg[NPB * 64];  // 32 KB
    int tid = threadIdx.x;
    int w = __builtin_amdgcn_readfirstlane(tid >> 6);
    int lane = tid & 63;
    int b = blockIdx.x, lo = b << 7;
    for (int t = tid; t < NPB * 64 / 4; t += 512)
        ((float4*)agg)[t] = make_float4(0.f, 0.f, 0.f, 0.f);
    __syncthreads();
    int base = bOff[b], cnt = bCnt[b], end = base + cnt;
    // self-loops: wave w handles nodes [w*16, w*16+16)
    for (int n = w * 16; n < w * 16 + 16; ++n) {
        int node = lo + n;
        if (node < N_NODES) {
            float si = isq[node];  // uniform -> s_load
            float v = bf2f(hin[(node << 6) + lane]);
            atomicAdd(&agg[(n << 6) + lane], v * (si * si));
        }
    }
    // edges: independent 8-edge groups, strided by wave
    int ngrp = (cnt + 7) >> 3;
    for (int g = w; g < ngrp; g += 8) {
        int jb = base + (g << 3);
        int2 rn[8];
#pragma unroll
        for (int q = 0; q < 8; ++q) rn[q] = eB[jb + q];  // uniform -> s_load
        unsigned int vv[8];
        int cl[8];
        float nn[8];
#pragma unroll
        for (int q = 0; q < 8; ++q) {
            int row = rn[q].x & 0x1FFFF;
            cl[q] = rn[q].x >> 17;
            nn[q] = (jb + q < end) ? __int_as_float(rn[q].y) : 0.0f;  // SALU mask
            vv[q] = hin[(row << 6) + lane];  // SGPR-base gather, 128B row
        }
#pragma unroll
        for (int q = 0; q < 8; ++q)
            atomicAdd(&agg[(cl[q] << 6) + lane], bf2f((ushort_t)vv[q]) * nn[q]);
    }
    __syncthreads();
    // epilogue: agg[128][64] @ W (packed bf16 in regs) + b, relu, bf16 store
    unsigned int wpk[32];
#pragma unroll
    for (int k2 = 0; k2 < 32; ++k2) wpk[k2] = wpG[(k2 << 6) + lane];
    float bias_r = bias[lane];
    for (int n = w * 16; n < w * 16 + 16; ++n) {
        int node = lo + n;
        if (node >= N_NODES) break;
        float o = bias_r;
#pragma unroll
        for (int q = 0; q < 16; ++q) {
            float4 av = *(const float4*)&agg[(n << 6) + (q << 2)];  // broadcast b128
            unsigned int p0 = wpk[2 * q], p1 = wpk[2 * q + 1];
            o = fmaf(av.x, __uint_as_float(p0 << 16), o);
            o = fmaf(av.y, __uint_as_float(p0 & 0xffff0000u), o);
            o = fmaf(av.z, __uint_as_float(p1 << 16), o);
            o = fmaf(av.w, __uint_as_float(p1 & 0xffff0000u), o);
        }
        o = o > 0.0f ? o : 0.0f;
        hout[(node << 6) + lane] = f2bf(o);
    }
}

// ---- layer 1: bucket-LDS aggregation over x (32 feats), 2 edges per wave-iter ----
__global__ void __launch_bounds__(512) fusedAgg32_kernel(
    const int2* __restrict__ eB, const int* __restrict__ bOff, const int* __restrict__ bCnt,
    const ushort_t* __restrict__ xbf, const float* __restrict__ isq,
    const unsigned int* __restrict__ wpG, const float* __restrict__ bias,
    ushort_t* __restrict__ hout) {
    __shared__ float agg[NPB * 32];  // 16 KB
    int tid = threadIdx.x;
    int w = __builtin_amdgcn_readfirstlane(tid >> 6);
    int lane = tid & 63;
    int f = lane & 31, half = lane >> 5;
    int b = blockIdx.x, lo = b << 7;
    for (int t = tid; t < NPB * 32 / 4; t += 512)
        ((float4*)agg)[t] = make_float4(0.f, 0.f, 0.f, 0.f);
    __syncthreads();
    int base = bOff[b], cnt = bCnt[b], end = base + cnt;
    // self-loops: 2 nodes per iteration (one per half-wave)
    for (int t = w * 8; t < w * 8 + 8; ++t) {
        int n0 = 2 * t, n1 = 2 * t + 1;
        int node0 = lo + n0, node1 = lo + n1;
        float si0 = (node0 < N_NODES) ? isq[node0] : 0.0f;
        float si1 = (node1 < N_NODES) ? isq[node1] : 0.0f;
        float dS = half ? si1 * si1 : si0 * si0;
        int nodeS = half ? node1 : node0;
        int nS = half ? n1 : n0;
        float v = bf2f(xbf[(nodeS << 5) + f]);  // over-read safe within ws
        atomicAdd(&agg[(nS << 5) + f], v * dS);
    }
    // edges: groups of 8 metadata -> 4 iterations x 2 edges
    int ngrp = (cnt + 7) >> 3;
    for (int g = w; g < ngrp; g += 8) {
        int jb = base + (g << 3);
        int2 rn[8];
#pragma unroll
        for (int q = 0; q < 8; ++q) rn[q] = eB[jb + q];  // uniform -> s_load
#pragma unroll
        for (int p = 0; p < 4; ++p) {
            int q0 = 2 * p, q1 = 2 * p + 1;
            int row0 = rn[q0].x & 0x1FFFF, cl0 = rn[q0].x >> 17;
            int row1 = rn[q1].x & 0x1FFFF, cl1 = rn[q1].x >> 17;
            float n0 = (jb + q0 < end) ? __int_as_float(rn[q0].y) : 0.0f;
            float n1 = (jb + q1 < end) ? __int_as_float(rn[q1].y) : 0.0f;
            int rowS = half ? row1 : row0;    // v_cndmask
            int clS = half ? cl1 : cl0;
            float nS = half ? n1 : n0;
            float v = bf2f(xbf[(rowS << 5) + f]);  // per-lane gather, 64B row/half
            atomicAdd(&agg[(clS << 5) + f], v * nS);
        }
    }
    __syncthreads();
    // epilogue: agg[128][32] @ W1 (packed bf16 regs) + b, relu, bf16 store
    unsigned int wpk[16];
#pragma unroll
    for (int k2 = 0; k2 < 16; ++k2) wpk[k2] = wpG[(k2 << 6) + lane];
    float bias_r = bias[lane];
    for (int n = w * 16; n < w * 16 + 16; ++n) {
        int node = lo + n;
        if (node >= N_NODES) break;
        float o = bias_r;
#pragma unroll
        for (int q = 0; q < 8; ++q) {
            float4 av = *(const float4*)&agg[(n << 5) + (q << 2)];
            unsigned int p0 = wpk[2 * q], p1 = wpk[2 * q + 1];
            o = fmaf(av.x, __uint_as_float(p0 << 16), o);
            o = fmaf(av.y, __uint_as_float(p0 & 0xffff0000u), o);
            o = fmaf(av.z, __uint_as_float(p1 << 16), o);
            o = fmaf(av.w, __uint_as_float(p1 & 0xffff0000u), o);
        }
        o = o > 0.0f ? o : 0.0f;
        hout[(node << 6) + lane] = f2bf(o);
    }
}

// ---- head: relu(h@Wl1+bl1)@Wl2+bl2 -> sigmoid -> p; weighted BCE -> loss ----
__global__ void head_kernel(const ushort_t* __restrict__ h, const float* __restrict__ Wl1,
                            const float* __restrict__ bl1, const float* __restrict__ Wl2,
                            const float* __restrict__ bl2, const float* __restrict__ labels,
                            const float* __restrict__ npos, float* __restrict__ out) {
    __shared__ float sW1[64 * 8];
    __shared__ float sb1[8];
    __shared__ float sW2[8];
    for (int t = threadIdx.x; t < 512; t += 256) sW1[t] = Wl1[t];
    if (threadIdx.x < 8) {
        sb1[threadIdx.x] = bl1[threadIdx.x];
        sW2[threadIdx.x] = Wl2[threadIdx.x];
    }
    __syncthreads();
    int i = blockIdx.x * 256 + threadIdx.x;
    float contrib = 0.0f;
    if (i < N_NODES) {
        const ushort4* hr4 = (const ushort4*)(h + (size_t)i * 64);
        float a[8];
#pragma unroll
        for (int j = 0; j < 8; ++j) a[j] = sb1[j];
#pragma unroll
        for (int kb = 0; kb < 16; ++kb) {
            ushort4 v4 = hr4[kb];
            float h0 = bf2f(v4.x), h1 = bf2f(v4.y), h2 = bf2f(v4.z), h3 = bf2f(v4.w);
#pragma unroll
            for (int j = 0; j < 8; ++j) {
                a[j] = fmaf(h0, sW1[(kb * 4 + 0) * 8 + j], a[j]);
                a[j] = fmaf(h1, sW1[(kb * 4 + 1) * 8 + j], a[j]);
                a[j] = fmaf(h2, sW1[(kb * 4 + 2) * 8 + j], a[j]);
                a[j] = fmaf(h3, sW1[(kb * 4 + 3) * 8 + j], a[j]);
            }
        }
        float z = bl2[0];
#pragma unroll
        for (int j = 0; j < 8; ++j) {
            float r = a[j] > 0.0f ? a[j] : 0.0f;
            z = fmaf(r, sW2[j], z);
        }
        float p = 1.0f / (1.0f + expf(-z));
        out[1 + i] = p;
        float y = labels[i];
        float np = *npos;
        float fn = (float)N_NODES;
        float wpos = fn / (2.0f * np);
        float wneg = fn / (2.0f * (fn - np));
        float wgt = y * wpos + (1.0f - y) * wneg;
        float lse = log1pf(expf(-fabsf(z)));
        float ls_pos = fminf(z, 0.0f) - lse;
        float ls_neg = fminf(-z, 0.0f) - lse;
        float bce = -(y * ls_pos + (1.0f - y) * ls_neg);
        contrib = wgt * bce / fn;
    }
    __shared__ float red[256];
    red[threadIdx.x] = contrib;
    __syncthreads();
    for (int s = 128; s > 0; s >>= 1) {
        if (threadIdx.x < s) red[threadIdx.x] += red[threadIdx.x + s];
        __syncthreads();
    }
    if (threadIdx.x == 0) atomicAdd(out, red[0]);
}

extern "C" void kernel_launch(void* const* d_in, const int* in_sizes, int n_in,
                              void* d_out, int out_size, void* d_ws, size_t ws_size,
                              hipStream_t stream) {
    const float* x      = (const float*)d_in[0];
    const int*   ei     = (const int*)d_in[1];
    const float* labels = (const float*)d_in[2];
    const float* W1  = (const float*)d_in[3];
    const float* b1  = (const float*)d_in[4];
    const float* W2  = (const float*)d_in[5];
    const float* b2  = (const float*)d_in[6];
    const float* W3  = (const float*)d_in[7];
    const float* b3  = (const float*)d_in[8];
    const float* Wl1 = (const float*)d_in[9];
    const float* bl1 = (const float*)d_in[10];
    const float* Wl2 = (const float*)d_in[11];
    const float* bl2 = (const float*)d_in[12];

    const int* row = ei;            // edge_index[0]
    const int* col = ei + N_EDGES;  // edge_index[1]
    float* out = (float*)d_out;

    // ---- workspace layout ----
    char* w = (char*)d_ws;
    int2*     eB   = (int2*)w;                                  // (E+8)*8B binned edges
    ushort_t* xbf  = (ushort_t*)(w + (size_t)(N_EDGES + 8) * 8);// N*32*2B
    ushort_t* hbfA = xbf + (size_t)N_NODES * 32;                // N*64*2B
    ushort_t* hbfB = hbfA + (size_t)N_NODES * 64;               // N*64*2B
    int*      bucketCnt = (int*)(hbfB + (size_t)N_NODES * 64);  // NBUCK
    int*      bucketOff = bucketCnt + NBUCK;                    // NBUCK
    int*      bcursor   = bucketOff + NBUCK;                    // NBUCK
    float*    isq  = (float*)(bcursor + NBUCK);                 // N
    float*    npos = isq + N_NODES;                             // 1
    unsigned int* wpG = (unsigned int*)(npos + 1);              // 80*64 u32

    hipMemsetAsync(bucketCnt, 0, NBUCK * sizeof(int), stream);
    hipMemsetAsync(npos, 0, sizeof(float), stream);
    hipMemsetAsync(out, 0, sizeof(float), stream);
    hipMemsetAsync(eB + N_EDGES, 0, 8 * sizeof(int2), stream);  // over-read slack (norm=0)

    const int BB = (N_EDGES + 4095) / 4096;  // 782
    const int XB = (N_NODES * 32 / 4 + 255) / 256;

    bucket_hist_kernel<<<1024, 256, 0, stream>>>(col, bucketCnt);
    bucket_scan_kernel<<<1, 1024, 0, stream>>>(bucketCnt, bucketOff, bcursor);
    bin_kernel<<<BB, 512, 0, stream>>>(row, col, bcursor, eB);
    csrlite_kernel<<<NBUCK, NPB, 0, stream>>>(eB, bucketOff, bucketCnt, isq, labels, npos);
    normpack_kernel<<<(N_EDGES + 255) / 256, 256, 0, stream>>>(eB, isq);
    xcast_kernel<<<XB, 256, 0, stream>>>(x, xbf);
    wpack_kernel<<<20, 256, 0, stream>>>(W1, W2, W3, wpG);

    fusedAgg32_kernel<<<NBUCK, 512, 0, stream>>>(eB, bucketOff, bucketCnt, xbf, isq,
                                                 wpG, b1, hbfA);
    fusedAgg64_kernel<<<NBUCK, 512, 0, stream>>>(eB, bucketOff, bucketCnt, hbfA, isq,
                                                 wpG + 16 * 64, b2, hbfB);
    fusedAgg64_kernel<<<NBUCK, 512, 0, stream>>>(eB, bucketOff, bucketCnt, hbfB, isq,
                                                 wpG + 48 * 64, b3, hbfA);

    head_kernel<<<(N_NODES + 255) / 256, 256, 0, stream>>>(hbfA, Wl1, bl1, Wl2, bl2, labels,
                                                           npos, out);
}

// Round 11
// 739.708 us; speedup vs baseline: 4.9087x; 4.9087x over previous
//
#include <hip/hip_runtime.h>
#include <math.h>

#define N_NODES 100000
#define N_EDGES 3200000
#define NPB 256                              // nodes per bucket
#define NBUCK ((N_NODES + NPB - 1) / NPB)    // 391
#define NPW 4                                // nodes per wave (fused kernels)

typedef unsigned short ushort_t;

static __device__ __forceinline__ float bf2f(ushort_t u) {
    return __uint_as_float(((unsigned int)u) << 16);
}
static __device__ __forceinline__ unsigned int f2bf_u(float f) {
    unsigned int x = __float_as_uint(f);
    unsigned int lsb = (x >> 16) & 1u;
    x += 0x7fffu + lsb;  // round-to-nearest-even
    return x >> 16;
}
static __device__ __forceinline__ ushort_t f2bf(float f) { return (ushort_t)f2bf_u(f); }

// ---- pass A: bucket histogram (LDS-aggregated) ----
__global__ void bucket_hist_kernel(const int* __restrict__ col, int* __restrict__ bucketCnt) {
    __shared__ int h[NBUCK];
    for (int t = threadIdx.x; t < NBUCK; t += 256) h[t] = 0;
    __syncthreads();
    for (int e = blockIdx.x * 256 + threadIdx.x; e < N_EDGES; e += gridDim.x * 256)
        atomicAdd(&h[col[e] >> 8], 1);
    __syncthreads();
    for (int t = threadIdx.x; t < NBUCK; t += 256)
        if (h[t]) atomicAdd(&bucketCnt[t], h[t]);
}

// ---- pass B: scan bucket counts -> bucketOff; init bcursor ----
__global__ void bucket_scan_kernel(const int* __restrict__ bucketCnt, int* __restrict__ bucketOff,
                                   int* __restrict__ bcursor) {
    __shared__ int tmp[512];
    int tx = threadIdx.x;
    int v = (tx < NBUCK) ? bucketCnt[tx] : 0;
    tmp[tx] = v;
    __syncthreads();
    for (int off = 1; off < 512; off <<= 1) {
        int t = (tx >= off) ? tmp[tx - off] : 0;
        __syncthreads();
        if (tx >= off) tmp[tx] += t;
        __syncthreads();
    }
    if (tx < NBUCK) {
        int o = tmp[tx] - v;
        bucketOff[tx] = o;
        bcursor[tx] = o;
    }
}

// ---- pass C: bin edges by bucket (block-aggregated append) ----
__global__ void bin_kernel(const int* __restrict__ row, const int* __restrict__ col,
                           int* __restrict__ bcursor, int2* __restrict__ tmpE) {
    __shared__ int hist[NBUCK];
    __shared__ int chunkOff[NBUCK];
    int tx = threadIdx.x;
    for (int t = tx; t < NBUCK; t += 512) hist[t] = 0;
    __syncthreads();
    int base = blockIdx.x * 4096;
    int myc[8], myr[8], myrank[8];
#pragma unroll 8
    for (int k = 0; k < 8; ++k) {
        int idx = base + k * 512 + tx;
        bool valid = idx < N_EDGES;
        int c = valid ? col[idx] : 0;
        int r = valid ? row[idx] : 0;
        myc[k] = c;
        myr[k] = r;
        myrank[k] = valid ? atomicAdd(&hist[c >> 8], 1) : 0;
    }
    __syncthreads();
    for (int t = tx; t < NBUCK; t += 512) {
        int hv = hist[t];
        chunkOff[t] = hv ? atomicAdd(&bcursor[t], hv) : 0;
    }
    __syncthreads();
#pragma unroll 8
    for (int k = 0; k < 8; ++k) {
        int idx = base + k * 512 + tx;
        if (idx < N_EDGES) {
            int pos = chunkOff[myc[k] >> 8] + myrank[k];
            tmpE[pos] = make_int2(myr[k], myc[k]);
        }
    }
}

// ---- pass D: per-bucket CSR: starts, isq, edgeRow; + npos reduction ----
__global__ void csr_kernel(const int2* __restrict__ tmpE, const int* __restrict__ bucketOff,
                           const int* __restrict__ bucketCnt, int* __restrict__ starts,
                           int* __restrict__ edgeRow, float* __restrict__ isq,
                           const float* __restrict__ labels, float* __restrict__ npos) {
    __shared__ int scnt[NPB];
    __shared__ int sscan[NPB];
    __shared__ int scur[NPB];
    __shared__ float red[NPB];
    int b = blockIdx.x;
    int lo = b * NPB;
    int nn = N_NODES - lo;
    if (nn > NPB) nn = NPB;
    int base = bucketOff[b];
    int ecnt = bucketCnt[b];
    int tx = threadIdx.x;
    scnt[tx] = 0;
    __syncthreads();
    for (int t = tx; t < ecnt; t += NPB) atomicAdd(&scnt[tmpE[base + t].y - lo], 1);
    __syncthreads();
    int v = scnt[tx];
    sscan[tx] = v;
    __syncthreads();
    for (int off = 1; off < NPB; off <<= 1) {
        int t = (tx >= off) ? sscan[tx - off] : 0;
        __syncthreads();
        if (tx >= off) sscan[tx] += t;
        __syncthreads();
    }
    int excl = sscan[tx] - v;
    scur[tx] = excl;
    float lab = 0.0f;
    if (tx < nn) {
        starts[lo + tx] = base + excl;
        isq[lo + tx] = rsqrtf((float)v + 1.0f);
        lab = labels[lo + tx];
    }
    if (b == NBUCK - 1 && tx == 0) starts[N_NODES] = N_EDGES;
    red[tx] = lab;
    __syncthreads();
    for (int s = NPB / 2; s > 0; s >>= 1) {
        if (tx < s) red[tx] += red[tx + s];
        __syncthreads();
    }
    if (tx == 0) atomicAdd(npos, red[0]);
    for (int t = tx; t < ecnt; t += NPB) {
        int2 rc = tmpE[base + t];
        int p = atomicAdd(&scur[rc.y - lo], 1);
        edgeRow[base + p] = rc.x;
    }
}

// ---- pass E: edgeRN[t] = {row, isq[row]*isq[owner]} (overwrites tmpE region) ----
__global__ void norm_fill_kernel(const int* __restrict__ starts, const int* __restrict__ edgeRow,
                                 const float* __restrict__ isq, int2* __restrict__ edgeRN) {
    int w = threadIdx.x >> 6;
    int lane = threadIdx.x & 63;
    int nodeBase = blockIdx.x * (4 * NPW) + w * NPW;
    for (int i = 0; i < NPW; ++i) {
        int node = nodeBase + i;
        int s = starts[node];
        int e = starts[node + 1];
        float si = isq[node];
        for (int t = s + lane; t < e; t += 64) {
            int r = edgeRow[t];
            edgeRN[t] = make_int2(r, __float_as_int(isq[r] * si));
        }
    }
}

// ---- x (fp32 N*32) -> bf16 table ----
__global__ void xcast_kernel(const float* __restrict__ x, ushort_t* __restrict__ xbf) {
    int i = blockIdx.x * 256 + threadIdx.x;  // group of 4
    if (i < (N_NODES * 32) / 4) {
        float4 v = ((const float4*)x)[i];
        ushort4 o;
        o.x = f2bf(v.x); o.y = f2bf(v.y); o.z = f2bf(v.z); o.w = f2bf(v.w);
        ((ushort4*)xbf)[i] = o;
    }
}

// ---- pack W1/W2/W3 into per-lane bf16x2 column tables ----
// layout: slot k2 in [0,80): [0,16)=W1, [16,48)=W2, [48,80)=W3; wp[k2*64+lane]
__global__ void wpack_kernel(const float* __restrict__ W1, const float* __restrict__ W2,
                             const float* __restrict__ W3, unsigned int* __restrict__ wp) {
    int t = blockIdx.x * 256 + threadIdx.x;
    if (t >= 80 * 64) return;
    int k2 = t >> 6, l = t & 63;
    const float* W;
    int kk;
    if (k2 < 16) { W = W1; kk = k2; }
    else if (k2 < 48) { W = W2; kk = k2 - 16; }
    else { W = W3; kk = k2 - 48; }
    float lo = W[(2 * kk) * 64 + l];
    float hi = W[(2 * kk + 1) * 64 + l];
    wp[t] = (f2bf_u(hi) << 16) | f2bf_u(lo);
}

// ---- layer 1 fused: agg(x)[32] -> @W[32x64]+b -> relu -> bf16 h ----
// scalar-pipe metadata; TWO independent node chains interleaved per wave
__global__ void fused32_kernel(const int* __restrict__ starts, const int2* __restrict__ edgeRN,
                               const ushort_t* __restrict__ xbf, const float* __restrict__ isq,
                               const unsigned int* __restrict__ wpG,
                               const float* __restrict__ bias, ushort_t* __restrict__ hout) {
    __shared__ float sAgg[4][2][32];
    int w = threadIdx.x >> 6;
    int lane = threadIdx.x & 63;
    int f = lane & 31, half = lane >> 5;
    unsigned int wpk[16];
#pragma unroll
    for (int k2 = 0; k2 < 16; ++k2) wpk[k2] = wpG[k2 * 64 + lane];
    float bias_r = bias[lane];
    int nodeBase = blockIdx.x * (4 * NPW) + w * NPW;
    for (int i = 0; i < NPW; i += 2) {
        int node0 = __builtin_amdgcn_readfirstlane(nodeBase + i);
        int node1 = node0 + 1;
        int sU0 = starts[node0];
        int eU0 = starts[node0 + 1];
        int sU1 = eU0;
        int eU1 = starts[node1 + 1];
        float si0 = isq[node0], si1 = isq[node1];
        float a0[2] = {0.0f, 0.0f}, a1[2] = {0.0f, 0.0f};
        int ng0 = (eU0 - sU0 + 7) >> 3;
        int ng1 = (eU1 - sU1 + 7) >> 3;
        int ng = ng0 > ng1 ? ng0 : ng1;
        for (int g = 0; g < ng; ++g) {
            int jb0 = sU0 + (g << 3), jb1 = sU1 + (g << 3);
            bool c0 = g < ng0, c1 = g < ng1;
            int2 rn0[8], rn1[8];
            if (c0) {
#pragma unroll
                for (int q = 0; q < 8; ++q) rn0[q] = edgeRN[jb0 + q];  // s_load
            }
            if (c1) {
#pragma unroll
                for (int q = 0; q < 8; ++q) rn1[q] = edgeRN[jb1 + q];  // s_load
            }
            unsigned int vv0[8], vv1[8];
            if (c0) {
#pragma unroll
                for (int q = 0; q < 8; ++q) vv0[q] = xbf[(rn0[q].x << 5) + f];
            }
            if (c1) {
#pragma unroll
                for (int q = 0; q < 8; ++q) vv1[q] = xbf[(rn1[q].x << 5) + f];
            }
            if (c0) {
#pragma unroll
                for (int q = 0; q < 8; ++q) {
                    float n = (jb0 + q < eU0) ? __int_as_float(rn0[q].y) : 0.0f;
                    a0[q & 1] = fmaf(bf2f((ushort_t)vv0[q]), n, a0[q & 1]);
                }
            }
            if (c1) {
#pragma unroll
                for (int q = 0; q < 8; ++q) {
                    float n = (jb1 + q < eU1) ? __int_as_float(rn1[q].y) : 0.0f;
                    a1[q & 1] = fmaf(bf2f((ushort_t)vv1[q]), n, a1[q & 1]);
                }
            }
        }
        float s0 = a0[0] + a0[1];  // halves hold identical sums
        float s1 = a1[0] + a1[1];
        if (half == 0) {
            s0 = fmaf(bf2f(xbf[(node0 << 5) + f]), si0 * si0, s0);  // self-loop
            s1 = fmaf(bf2f(xbf[(node1 << 5) + f]), si1 * si1, s1);
            sAgg[w][0][f] = s0;
            sAgg[w][1][f] = s1;
        }
        for (int p = 0; p < 2; ++p) {
            int node = node0 + p;
            float o = bias_r;
#pragma unroll
            for (int q = 0; q < 8; ++q) {  // 32-dot: 8x b128 broadcast + packed W regs
                float4 av = *(const float4*)&sAgg[w][p][q * 4];
                unsigned int p0 = wpk[2 * q], p1 = wpk[2 * q + 1];
                o = fmaf(av.x, __uint_as_float(p0 << 16), o);
                o = fmaf(av.y, __uint_as_float(p0 & 0xffff0000u), o);
                o = fmaf(av.z, __uint_as_float(p1 << 16), o);
                o = fmaf(av.w, __uint_as_float(p1 & 0xffff0000u), o);
            }
            o = o > 0.0f ? o : 0.0f;
            hout[(node << 6) + lane] = f2bf(o);
        }
    }
}

// ---- layers 2/3 fused: agg(h)[64] -> @W[64x64]+b -> relu -> bf16 h ----
// scalar-pipe metadata; TWO independent node chains interleaved per wave
__global__ void fused64_kernel(const int* __restrict__ starts, const int2* __restrict__ edgeRN,
                               const ushort_t* __restrict__ hin, const float* __restrict__ isq,
                               const unsigned int* __restrict__ wpG,
                               const float* __restrict__ bias, ushort_t* __restrict__ hout) {
    __shared__ float sAgg[4][2][64];
    int w = threadIdx.x >> 6;
    int lane = threadIdx.x & 63;
    unsigned int wpk[32];
#pragma unroll
    for (int k2 = 0; k2 < 32; ++k2) wpk[k2] = wpG[k2 * 64 + lane];
    float bias_r = bias[lane];
    int nodeBase = blockIdx.x * (4 * NPW) + w * NPW;
    for (int i = 0; i < NPW; i += 2) {
        int node0 = __builtin_amdgcn_readfirstlane(nodeBase + i);
        int node1 = node0 + 1;
        int sU0 = starts[node0];
        int eU0 = starts[node0 + 1];
        int sU1 = eU0;
        int eU1 = starts[node1 + 1];
        float si0 = isq[node0], si1 = isq[node1];
        float a0[2], a1[2];
        a0[0] = bf2f(hin[(node0 << 6) + lane]) * (si0 * si0);  // self-loop
        a1[0] = bf2f(hin[(node1 << 6) + lane]) * (si1 * si1);
        a0[1] = 0.0f; a1[1] = 0.0f;
        int ng0 = (eU0 - sU0 + 7) >> 3;
        int ng1 = (eU1 - sU1 + 7) >> 3;
        int ng = ng0 > ng1 ? ng0 : ng1;
        for (int g = 0; g < ng; ++g) {
            int jb0 = sU0 + (g << 3), jb1 = sU1 + (g << 3);
            bool c0 = g < ng0, c1 = g < ng1;
            int2 rn0[8], rn1[8];
            if (c0) {
#pragma unroll
                for (int q = 0; q < 8; ++q) rn0[q] = edgeRN[jb0 + q];  // s_load
            }
            if (c1) {
#pragma unroll
                for (int q = 0; q < 8; ++q) rn1[q] = edgeRN[jb1 + q];  // s_load
            }
            unsigned int vv0[8], vv1[8];
            if (c0) {
#pragma unroll
                for (int q = 0; q < 8; ++q) vv0[q] = hin[(rn0[q].x << 6) + lane];
            }
            if (c1) {
#pragma unroll
                for (int q = 0; q < 8; ++q) vv1[q] = hin[(rn1[q].x << 6) + lane];
            }
            if (c0) {
#pragma unroll
                for (int q = 0; q < 8; ++q) {
                    float n = (jb0 + q < eU0) ? __int_as_float(rn0[q].y) : 0.0f;
                    a0[q & 1] = fmaf(bf2f((ushort_t)vv0[q]), n, a0[q & 1]);
                }
            }
            if (c1) {
#pragma unroll
                for (int q = 0; q < 8; ++q) {
                    float n = (jb1 + q < eU1) ? __int_as_float(rn1[q].y) : 0.0f;
                    a1[q & 1] = fmaf(bf2f((ushort_t)vv1[q]), n, a1[q & 1]);
                }
            }
        }
        sAgg[w][0][lane] = a0[0] + a0[1];
        sAgg[w][1][lane] = a1[0] + a1[1];
        for (int p = 0; p < 2; ++p) {
            int node = node0 + p;
            float o = bias_r;
#pragma unroll
            for (int q = 0; q < 16; ++q) {  // 64-dot: 16x b128 broadcast + packed W regs
                float4 av = *(const float4*)&sAgg[w][p][q * 4];
                unsigned int p0 = wpk[2 * q], p1 = wpk[2 * q + 1];
                o = fmaf(av.x, __uint_as_float(p0 << 16), o);
                o = fmaf(av.y, __uint_as_float(p0 & 0xffff0000u), o);
                o = fmaf(av.z, __uint_as_float(p1 << 16), o);
                o = fmaf(av.w, __uint_as_float(p1 & 0xffff0000u), o);
            }
            o = o > 0.0f ? o : 0.0f;
            hout[(node << 6) + lane] = f2bf(o);
        }
    }
}

// ---- head: relu(h@Wl1+bl1)@Wl2+bl2 -> sigmoid -> p; weighted BCE -> loss ----
__global__ void head_kernel(const ushort_t* __restrict__ h, const float* __restrict__ Wl1,
                            const float* __restrict__ bl1, const float* __restrict__ Wl2,
                            const float* __restrict__ bl2, const float* __restrict__ labels,
                            const float* __restrict__ npos, float* __restrict__ out) {
    __shared__ float sW1[64 * 8];
    __shared__ float sb1[8];
    __shared__ float sW2[8];
    for (int t = threadIdx.x; t < 512; t += 256) sW1[t] = Wl1[t];
    if (threadIdx.x < 8) {
        sb1[threadIdx.x] = bl1[threadIdx.x];
        sW2[threadIdx.x] = Wl2[threadIdx.x];
    }
    __syncthreads();
    int i = blockIdx.x * 256 + threadIdx.x;
    float contrib = 0.0f;
    if (i < N_NODES) {
        const ushort4* hr4 = (const ushort4*)(h + (size_t)i * 64);
        float a[8];
#pragma unroll
        for (int j = 0; j < 8; ++j) a[j] = sb1[j];
#pragma unroll
        for (int kb = 0; kb < 16; ++kb) {
            ushort4 v4 = hr4[kb];
            float h0 = bf2f(v4.x), h1 = bf2f(v4.y), h2 = bf2f(v4.z), h3 = bf2f(v4.w);
#pragma unroll
            for (int j = 0; j < 8; ++j) {
                a[j] = fmaf(h0, sW1[(kb * 4 + 0) * 8 + j], a[j]);
                a[j] = fmaf(h1, sW1[(kb * 4 + 1) * 8 + j], a[j]);
                a[j] = fmaf(h2, sW1[(kb * 4 + 2) * 8 + j], a[j]);
                a[j] = fmaf(h3, sW1[(kb * 4 + 3) * 8 + j], a[j]);
            }
        }
        float z = bl2[0];
#pragma unroll
        for (int j = 0; j < 8; ++j) {
            float r = a[j] > 0.0f ? a[j] : 0.0f;
            z = fmaf(r, sW2[j], z);
        }
        float p = 1.0f / (1.0f + expf(-z));
        out[1 + i] = p;
        float y = labels[i];
        float np = *npos;
        float fn = (float)N_NODES;
        float wpos = fn / (2.0f * np);
        float wneg = fn / (2.0f * (fn - np));
        float wgt = y * wpos + (1.0f - y) * wneg;
        float lse = log1pf(expf(-fabsf(z)));
        float ls_pos = fminf(z, 0.0f) - lse;
        float ls_neg = fminf(-z, 0.0f) - lse;
        float bce = -(y * ls_pos + (1.0f - y) * ls_neg);
        contrib = wgt * bce / fn;
    }
    __shared__ float red[256];
    red[threadIdx.x] = contrib;
    __syncthreads();
    for (int s = 128; s > 0; s >>= 1) {
        if (threadIdx.x < s) red[threadIdx.x] += red[threadIdx.x + s];
        __syncthreads();
    }
    if (threadIdx.x == 0) atomicAdd(out, red[0]);
}

extern "C" void kernel_launch(void* const* d_in, const int* in_sizes, int n_in,
                              void* d_out, int out_size, void* d_ws, size_t ws_size,
                              hipStream_t stream) {
    const float* x      = (const float*)d_in[0];
    const int*   ei     = (const int*)d_in[1];
    const float* labels = (const float*)d_in[2];
    const float* W1  = (const float*)d_in[3];
    const float* b1  = (const float*)d_in[4];
    const float* W2  = (const float*)d_in[5];
    const float* b2  = (const float*)d_in[6];
    const float* W3  = (const float*)d_in[7];
    const float* b3  = (const float*)d_in[8];
    const float* Wl1 = (const float*)d_in[9];
    const float* bl1 = (const float*)d_in[10];
    const float* Wl2 = (const float*)d_in[11];
    const float* bl2 = (const float*)d_in[12];

    const int* row = ei;            // edge_index[0]
    const int* col = ei + N_EDGES;  // edge_index[1]
    float* out = (float*)d_out;

    // ---- workspace layout (tmpE region is reused as edgeRN after csr) ----
    char* w = (char*)d_ws;
    int2*     tmpE    = (int2*)w;                               // E*8B
    int2*     edgeRN  = (int2*)w;                               // alias: E*8B
    int*      edgeRow = (int*)(w + (size_t)N_EDGES * 8);        // E*4B (also over-read slack)
    ushort_t* xbf     = (ushort_t*)(edgeRow + N_EDGES);         // N*32*2B
    ushort_t* hbfA    = xbf + (size_t)N_NODES * 32;             // N*64*2B
    ushort_t* hbfB    = hbfA + (size_t)N_NODES * 64;            // N*64*2B
    int*      starts  = (int*)(hbfB + (size_t)N_NODES * 64);    // N+1
    int*      bucketCnt = starts + (N_NODES + 1);               // NBUCK
    int*      bucketOff = bucketCnt + NBUCK;                    // NBUCK
    int*      bcursor   = bucketOff + NBUCK;                    // NBUCK
    float*    isq  = (float*)(bcursor + NBUCK);                 // N
    float*    npos = isq + N_NODES;                             // 1
    unsigned int* wpG = (unsigned int*)(npos + 1);              // 80*64 u32

    hipMemsetAsync(bucketCnt, 0, NBUCK * sizeof(int), stream);
    hipMemsetAsync(npos, 0, sizeof(float), stream);
    hipMemsetAsync(out, 0, sizeof(float), stream);

    const int FB = N_NODES / (4 * NPW);      // 6250 (fused/norm_fill blocks)
    const int BB = (N_EDGES + 4095) / 4096;  // 782
    const int XB = (N_NODES * 32 / 4 + 255) / 256;

    bucket_hist_kernel<<<1024, 256, 0, stream>>>(col, bucketCnt);
    bucket_scan_kernel<<<1, 512, 0, stream>>>(bucketCnt, bucketOff, bcursor);
    bin_kernel<<<BB, 512, 0, stream>>>(row, col, bcursor, tmpE);
    csr_kernel<<<NBUCK, NPB, 0, stream>>>(tmpE, bucketOff, bucketCnt, starts, edgeRow, isq,
                                          labels, npos);
    norm_fill_kernel<<<FB, 256, 0, stream>>>(starts, edgeRow, isq, edgeRN);
    xcast_kernel<<<XB, 256, 0, stream>>>(x, xbf);
    wpack_kernel<<<20, 256, 0, stream>>>(W1, W2, W3, wpG);

    fused32_kernel<<<FB, 256, 0, stream>>>(starts, edgeRN, xbf, isq, wpG, b1, hbfA);
    fused64_kernel<<<FB, 256, 0, stream>>>(starts, edgeRN, hbfA, isq, wpG + 16 * 64, b2, hbfB);
    fused64_kernel<<<FB, 256, 0, stream>>>(starts, edgeRN, hbfB, isq, wpG + 48 * 64, b3, hbfA);

    head_kernel<<<(N_NODES + 255) / 256, 256, 0, stream>>>(hbfA, Wl1, bl1, Wl2, bl2, labels,
                                                           npos, out);
}

// Round 12
// 415.286 us; speedup vs baseline: 8.7433x; 1.7812x over previous
//
#include <hip/hip_runtime.h>
#include <math.h>

#define N_NODES 100000
#define N_EDGES 3200000
#define NPB 256                              // nodes per bucket
#define NBUCK ((N_NODES + NPB - 1) / NPB)    // 391
#define NPW 4                                // nodes per wave (fused kernels)

typedef unsigned short ushort_t;

static __device__ __forceinline__ float bf2f(ushort_t u) {
    return __uint_as_float(((unsigned int)u) << 16);
}
static __device__ __forceinline__ unsigned int f2bf_u(float f) {
    unsigned int x = __float_as_uint(f);
    unsigned int lsb = (x >> 16) & 1u;
    x += 0x7fffu + lsb;  // round-to-nearest-even
    return x >> 16;
}
static __device__ __forceinline__ ushort_t f2bf(float f) { return (ushort_t)f2bf_u(f); }

// ---- pass A: bucket histogram (LDS-aggregated) ----
__global__ void bucket_hist_kernel(const int* __restrict__ col, int* __restrict__ bucketCnt) {
    __shared__ int h[NBUCK];
    for (int t = threadIdx.x; t < NBUCK; t += 256) h[t] = 0;
    __syncthreads();
    for (int e = blockIdx.x * 256 + threadIdx.x; e < N_EDGES; e += gridDim.x * 256)
        atomicAdd(&h[col[e] >> 8], 1);
    __syncthreads();
    for (int t = threadIdx.x; t < NBUCK; t += 256)
        if (h[t]) atomicAdd(&bucketCnt[t], h[t]);
}

// ---- pass B: scan bucket counts -> bucketOff; init bcursor ----
__global__ void bucket_scan_kernel(const int* __restrict__ bucketCnt, int* __restrict__ bucketOff,
                                   int* __restrict__ bcursor) {
    __shared__ int tmp[512];
    int tx = threadIdx.x;
    int v = (tx < NBUCK) ? bucketCnt[tx] : 0;
    tmp[tx] = v;
    __syncthreads();
    for (int off = 1; off < 512; off <<= 1) {
        int t = (tx >= off) ? tmp[tx - off] : 0;
        __syncthreads();
        if (tx >= off) tmp[tx] += t;
        __syncthreads();
    }
    if (tx < NBUCK) {
        int o = tmp[tx] - v;
        bucketOff[tx] = o;
        bcursor[tx] = o;
    }
}

// ---- pass C: bin edges by bucket (block-aggregated append) ----
__global__ void bin_kernel(const int* __restrict__ row, const int* __restrict__ col,
                           int* __restrict__ bcursor, int2* __restrict__ tmpE) {
    __shared__ int hist[NBUCK];
    __shared__ int chunkOff[NBUCK];
    int tx = threadIdx.x;
    for (int t = tx; t < NBUCK; t += 512) hist[t] = 0;
    __syncthreads();
    int base = blockIdx.x * 4096;
    int myc[8], myr[8], myrank[8];
#pragma unroll 8
    for (int k = 0; k < 8; ++k) {
        int idx = base + k * 512 + tx;
        bool valid = idx < N_EDGES;
        int c = valid ? col[idx] : 0;
        int r = valid ? row[idx] : 0;
        myc[k] = c;
        myr[k] = r;
        myrank[k] = valid ? atomicAdd(&hist[c >> 8], 1) : 0;
    }
    __syncthreads();
    for (int t = tx; t < NBUCK; t += 512) {
        int hv = hist[t];
        chunkOff[t] = hv ? atomicAdd(&bcursor[t], hv) : 0;
    }
    __syncthreads();
#pragma unroll 8
    for (int k = 0; k < 8; ++k) {
        int idx = base + k * 512 + tx;
        if (idx < N_EDGES) {
            int pos = chunkOff[myc[k] >> 8] + myrank[k];
            tmpE[pos] = make_int2(myr[k], myc[k]);
        }
    }
}

// ---- pass D: per-bucket CSR: starts, isq, edgeRow; + npos reduction ----
__global__ void csr_kernel(const int2* __restrict__ tmpE, const int* __restrict__ bucketOff,
                           const int* __restrict__ bucketCnt, int* __restrict__ starts,
                           int* __restrict__ edgeRow, float* __restrict__ isq,
                           const float* __restrict__ labels, float* __restrict__ npos) {
    __shared__ int scnt[NPB];
    __shared__ int sscan[NPB];
    __shared__ int scur[NPB];
    __shared__ float red[NPB];
    int b = blockIdx.x;
    int lo = b * NPB;
    int nn = N_NODES - lo;
    if (nn > NPB) nn = NPB;
    int base = bucketOff[b];
    int ecnt = bucketCnt[b];
    int tx = threadIdx.x;
    scnt[tx] = 0;
    __syncthreads();
    for (int t = tx; t < ecnt; t += NPB) atomicAdd(&scnt[tmpE[base + t].y - lo], 1);
    __syncthreads();
    int v = scnt[tx];
    sscan[tx] = v;
    __syncthreads();
    for (int off = 1; off < NPB; off <<= 1) {
        int t = (tx >= off) ? sscan[tx - off] : 0;
        __syncthreads();
        if (tx >= off) sscan[tx] += t;
        __syncthreads();
    }
    int excl = sscan[tx] - v;
    scur[tx] = excl;
    float lab = 0.0f;
    if (tx < nn) {
        starts[lo + tx] = base + excl;
        isq[lo + tx] = rsqrtf((float)v + 1.0f);
        lab = labels[lo + tx];
    }
    if (b == NBUCK - 1 && tx == 0) starts[N_NODES] = N_EDGES;
    red[tx] = lab;
    __syncthreads();
    for (int s = NPB / 2; s > 0; s >>= 1) {
        if (tx < s) red[tx] += red[tx + s];
        __syncthreads();
    }
    if (tx == 0) atomicAdd(npos, red[0]);
    for (int t = tx; t < ecnt; t += NPB) {
        int2 rc = tmpE[base + t];
        int p = atomicAdd(&scur[rc.y - lo], 1);
        edgeRow[base + p] = rc.x;
    }
}

// ---- x (fp32 N*32) -> bf16 table PRE-SCALED by isq[node] ----
__global__ void xcast_kernel(const float* __restrict__ x, const float* __restrict__ isq,
                             ushort_t* __restrict__ xs) {
    int i = blockIdx.x * 256 + threadIdx.x;  // group of 4 floats; node = i>>3
    if (i < (N_NODES * 32) / 4) {
        float s = isq[i >> 3];
        float4 v = ((const float4*)x)[i];
        ushort4 o;
        o.x = f2bf(v.x * s); o.y = f2bf(v.y * s); o.z = f2bf(v.z * s); o.w = f2bf(v.w * s);
        ((ushort4*)xs)[i] = o;
    }
}

// ---- pack W1/W2/W3 into per-lane bf16x2 column tables ----
// layout: slot k2 in [0,80): [0,16)=W1, [16,48)=W2, [48,80)=W3; wp[k2*64+lane]
__global__ void wpack_kernel(const float* __restrict__ W1, const float* __restrict__ W2,
                             const float* __restrict__ W3, unsigned int* __restrict__ wp) {
    int t = blockIdx.x * 256 + threadIdx.x;
    if (t >= 80 * 64) return;
    int k2 = t >> 6, l = t & 63;
    const float* W;
    int kk;
    if (k2 < 16) { W = W1; kk = k2; }
    else if (k2 < 48) { W = W2; kk = k2 - 16; }
    else { W = W3; kk = k2 - 48; }
    float lo = W[(2 * kk) * 64 + l];
    float hi = W[(2 * kk + 1) * 64 + l];
    wp[t] = (f2bf_u(hi) << 16) | f2bf_u(lo);
}

// ---- layer 1 fused: agg(xs)[32] -> @W[32x64]+b -> relu -> bf16 hs (scaled) ----
// pre-scaled table: per edge = gather + fma(v, {1,0}); *isq[col] hoisted out
__global__ void fused32_kernel(const int* __restrict__ starts, const int* __restrict__ edgeRow,
                               const ushort_t* __restrict__ xs, const float* __restrict__ isq,
                               const unsigned int* __restrict__ wpG,
                               const float* __restrict__ bias, ushort_t* __restrict__ hout) {
    __shared__ float sAgg[4][32];
    int w = threadIdx.x >> 6;
    int lane = threadIdx.x & 63;
    int f = lane & 31, half = lane >> 5;
    unsigned int wpk[16];
#pragma unroll
    for (int k2 = 0; k2 < 16; ++k2) wpk[k2] = wpG[k2 * 64 + lane];
    float bias_r = bias[lane];
    int nodeBase = blockIdx.x * (4 * NPW) + w * NPW;
    for (int i = 0; i < NPW; ++i) {
        int node = __builtin_amdgcn_readfirstlane(nodeBase + i);
        int sU = starts[node];
        int eU = starts[node + 1];
        float sic = isq[node];
        float acc[4] = {0.0f, 0.0f, 0.0f, 0.0f};
        int ngrp = (eU - sU + 15) >> 4;
        int jb = sU;
        for (int g = 0; g < ngrp; ++g) {
            int rows[16];
#pragma unroll
            for (int q = 0; q < 16; ++q) rows[q] = edgeRow[jb + q];  // uniform -> s_load
            unsigned int vv[16];
#pragma unroll
            for (int q = 0; q < 16; ++q) vv[q] = xs[(rows[q] << 5) + f];  // 16 in flight
#pragma unroll
            for (int q = 0; q < 16; ++q) {
                float n = (jb + q < eU) ? 1.0f : 0.0f;  // SALU mask
                acc[q & 3] = fmaf(bf2f((ushort_t)vv[q]), n, acc[q & 3]);
            }
            jb += 16;
        }
        float accsum = (acc[0] + acc[1]) + (acc[2] + acc[3]);  // halves identical
        if (half == 0) {
            accsum += bf2f(xs[(node << 5) + f]);       // self-loop (xs has isq folded)
            sAgg[w][f] = accsum * sic;                 // * isq[col] hoisted
        }
        float o = bias_r;
#pragma unroll
        for (int q = 0; q < 8; ++q) {  // 32-dot: 8x b128 broadcast + packed W regs
            float4 av = *(const float4*)&sAgg[w][q * 4];
            unsigned int p0 = wpk[2 * q], p1 = wpk[2 * q + 1];
            o = fmaf(av.x, __uint_as_float(p0 << 16), o);
            o = fmaf(av.y, __uint_as_float(p0 & 0xffff0000u), o);
            o = fmaf(av.z, __uint_as_float(p1 << 16), o);
            o = fmaf(av.w, __uint_as_float(p1 & 0xffff0000u), o);
        }
        o = o > 0.0f ? o : 0.0f;
        hout[(node << 6) + lane] = f2bf(o * sic);  // write SCALED for next layer's gather
    }
}

// ---- layers 2/3 fused: agg(hs)[64] -> @W[64x64]+b -> relu -> bf16 out ----
// outScaled=1: write h*isq (for next gather); 0: write h (for head)
__global__ void fused64_kernel(const int* __restrict__ starts, const int* __restrict__ edgeRow,
                               const ushort_t* __restrict__ hs, const float* __restrict__ isq,
                               const unsigned int* __restrict__ wpG,
                               const float* __restrict__ bias, ushort_t* __restrict__ hout,
                               int outScaled) {
    __shared__ float sAgg[4][64];
    int w = threadIdx.x >> 6;
    int lane = threadIdx.x & 63;
    unsigned int wpk[32];
#pragma unroll
    for (int k2 = 0; k2 < 32; ++k2) wpk[k2] = wpG[k2 * 64 + lane];
    float bias_r = bias[lane];
    int nodeBase = blockIdx.x * (4 * NPW) + w * NPW;
    for (int i = 0; i < NPW; ++i) {
        int node = __builtin_amdgcn_readfirstlane(nodeBase + i);
        int sU = starts[node];
        int eU = starts[node + 1];
        float sic = isq[node];
        float acc[4];
        acc[0] = bf2f(hs[(node << 6) + lane]);  // self-loop (hs has isq[node] folded)
        acc[1] = 0.0f; acc[2] = 0.0f; acc[3] = 0.0f;
        int ngrp = (eU - sU + 15) >> 4;
        int jb = sU;
        for (int g = 0; g < ngrp; ++g) {
            int rows[16];
#pragma unroll
            for (int q = 0; q < 16; ++q) rows[q] = edgeRow[jb + q];  // uniform -> s_load
            unsigned int vv[16];
#pragma unroll
            for (int q = 0; q < 16; ++q) vv[q] = hs[(rows[q] << 6) + lane];  // 16 in flight
#pragma unroll
            for (int q = 0; q < 16; ++q) {
                float n = (jb + q < eU) ? 1.0f : 0.0f;  // SALU mask
                acc[q & 3] = fmaf(bf2f((ushort_t)vv[q]), n, acc[q & 3]);
            }
            jb += 16;
        }
        sAgg[w][lane] = ((acc[0] + acc[1]) + (acc[2] + acc[3])) * sic;  // *isq[col] hoisted
        float o = bias_r;
#pragma unroll
        for (int q = 0; q < 16; ++q) {  // 64-dot: 16x b128 broadcast + packed W regs
            float4 av = *(const float4*)&sAgg[w][q * 4];
            unsigned int p0 = wpk[2 * q], p1 = wpk[2 * q + 1];
            o = fmaf(av.x, __uint_as_float(p0 << 16), o);
            o = fmaf(av.y, __uint_as_float(p0 & 0xffff0000u), o);
            o = fmaf(av.z, __uint_as_float(p1 << 16), o);
            o = fmaf(av.w, __uint_as_float(p1 & 0xffff0000u), o);
        }
        o = o > 0.0f ? o : 0.0f;
        float scale = outScaled ? sic : 1.0f;
        hout[(node << 6) + lane] = f2bf(o * scale);
    }
}

// ---- head: relu(h@Wl1+bl1)@Wl2+bl2 -> sigmoid -> p; weighted BCE -> loss ----
__global__ void head_kernel(const ushort_t* __restrict__ h, const float* __restrict__ Wl1,
                            const float* __restrict__ bl1, const float* __restrict__ Wl2,
                            const float* __restrict__ bl2, const float* __restrict__ labels,
                            const float* __restrict__ npos, float* __restrict__ out) {
    __shared__ float sW1[64 * 8];
    __shared__ float sb1[8];
    __shared__ float sW2[8];
    for (int t = threadIdx.x; t < 512; t += 256) sW1[t] = Wl1[t];
    if (threadIdx.x < 8) {
        sb1[threadIdx.x] = bl1[threadIdx.x];
        sW2[threadIdx.x] = Wl2[threadIdx.x];
    }
    __syncthreads();
    int i = blockIdx.x * 256 + threadIdx.x;
    float contrib = 0.0f;
    if (i < N_NODES) {
        const ushort4* hr4 = (const ushort4*)(h + (size_t)i * 64);
        float a[8];
#pragma unroll
        for (int j = 0; j < 8; ++j) a[j] = sb1[j];
#pragma unroll
        for (int kb = 0; kb < 16; ++kb) {
            ushort4 v4 = hr4[kb];
            float h0 = bf2f(v4.x), h1 = bf2f(v4.y), h2 = bf2f(v4.z), h3 = bf2f(v4.w);
#pragma unroll
            for (int j = 0; j < 8; ++j) {
                a[j] = fmaf(h0, sW1[(kb * 4 + 0) * 8 + j], a[j]);
                a[j] = fmaf(h1, sW1[(kb * 4 + 1) * 8 + j], a[j]);
                a[j] = fmaf(h2, sW1[(kb * 4 + 2) * 8 + j], a[j]);
                a[j] = fmaf(h3, sW1[(kb * 4 + 3) * 8 + j], a[j]);
            }
        }
        float z = bl2[0];
#pragma unroll
        for (int j = 0; j < 8; ++j) {
            float r = a[j] > 0.0f ? a[j] : 0.0f;
            z = fmaf(r, sW2[j], z);
        }
        float p = 1.0f / (1.0f + expf(-z));
        out[1 + i] = p;
        float y = labels[i];
        float np = *npos;
        float fn = (float)N_NODES;
        float wpos = fn / (2.0f * np);
        float wneg = fn / (2.0f * (fn - np));
        float wgt = y * wpos + (1.0f - y) * wneg;
        float lse = log1pf(expf(-fabsf(z)));
        float ls_pos = fminf(z, 0.0f) - lse;
        float ls_neg = fminf(-z, 0.0f) - lse;
        float bce = -(y * ls_pos + (1.0f - y) * ls_neg);
        contrib = wgt * bce / fn;
    }
    __shared__ float red[256];
    red[threadIdx.x] = contrib;
    __syncthreads();
    for (int s = 128; s > 0; s >>= 1) {
        if (threadIdx.x < s) red[threadIdx.x] += red[threadIdx.x + s];
        __syncthreads();
    }
    if (threadIdx.x == 0) atomicAdd(out, red[0]);
}

extern "C" void kernel_launch(void* const* d_in, const int* in_sizes, int n_in,
                              void* d_out, int out_size, void* d_ws, size_t ws_size,
                              hipStream_t stream) {
    const float* x      = (const float*)d_in[0];
    const int*   ei     = (const int*)d_in[1];
    const float* labels = (const float*)d_in[2];
    const float* W1  = (const float*)d_in[3];
    const float* b1  = (const float*)d_in[4];
    const float* W2  = (const float*)d_in[5];
    const float* b2  = (const float*)d_in[6];
    const float* W3  = (const float*)d_in[7];
    const float* b3  = (const float*)d_in[8];
    const float* Wl1 = (const float*)d_in[9];
    const float* bl1 = (const float*)d_in[10];
    const float* Wl2 = (const float*)d_in[11];
    const float* bl2 = (const float*)d_in[12];

    const int* row = ei;            // edge_index[0]
    const int* col = ei + N_EDGES;  // edge_index[1]
    float* out = (float*)d_out;

    // ---- workspace layout ----
    char* w = (char*)d_ws;
    int2*     tmpE    = (int2*)w;                               // E*8B
    int*      edgeRow = (int*)(w + (size_t)N_EDGES * 8);        // (E+16)*4B (pad for 16-grp)
    ushort_t* xbf     = (ushort_t*)(edgeRow + N_EDGES + 16);    // N*32*2B (scaled)
    ushort_t* hbfA    = xbf + (size_t)N_NODES * 32;             // N*64*2B
    ushort_t* hbfB    = hbfA + (size_t)N_NODES * 64;            // N*64*2B
    int*      starts  = (int*)(hbfB + (size_t)N_NODES * 64);    // N+1
    int*      bucketCnt = starts + (N_NODES + 1);               // NBUCK
    int*      bucketOff = bucketCnt + NBUCK;                    // NBUCK
    int*      bcursor   = bucketOff + NBUCK;                    // NBUCK
    float*    isq  = (float*)(bcursor + NBUCK);                 // N
    float*    npos = isq + N_NODES;                             // 1
    unsigned int* wpG = (unsigned int*)(npos + 1);              // 80*64 u32

    hipMemsetAsync(bucketCnt, 0, NBUCK * sizeof(int), stream);
    hipMemsetAsync(npos, 0, sizeof(float), stream);
    hipMemsetAsync(out, 0, sizeof(float), stream);
    hipMemsetAsync(edgeRow + N_EDGES, 0, 16 * sizeof(int), stream);  // over-read slack

    const int FB = N_NODES / (4 * NPW);      // 6250 (fused blocks)
    const int BB = (N_EDGES + 4095) / 4096;  // 782
    const int XB = (N_NODES * 32 / 4 + 255) / 256;

    bucket_hist_kernel<<<1024, 256, 0, stream>>>(col, bucketCnt);
    bucket_scan_kernel<<<1, 512, 0, stream>>>(bucketCnt, bucketOff, bcursor);
    bin_kernel<<<BB, 512, 0, stream>>>(row, col, bcursor, tmpE);
    csr_kernel<<<NBUCK, NPB, 0, stream>>>(tmpE, bucketOff, bucketCnt, starts, edgeRow, isq,
                                          labels, npos);
    xcast_kernel<<<XB, 256, 0, stream>>>(x, isq, xbf);
    wpack_kernel<<<20, 256, 0, stream>>>(W1, W2, W3, wpG);

    fused32_kernel<<<FB, 256, 0, stream>>>(starts, edgeRow, xbf, isq, wpG, b1, hbfA);
    fused64_kernel<<<FB, 256, 0, stream>>>(starts, edgeRow, hbfA, isq, wpG + 16 * 64, b2,
                                           hbfB, 1);
    fused64_kernel<<<FB, 256, 0, stream>>>(starts, edgeRow, hbfB, isq, wpG + 48 * 64, b3,
                                           hbfA, 0);

    head_kernel<<<(N_NODES + 255) / 256, 256, 0, stream>>>(hbfA, Wl1, bl1, Wl2, bl2, labels,
                                                           npos, out);
}